// Round 1
// baseline (1230.678 us; speedup 1.0000x reference)
//
#include <hip/hip_runtime.h>
#include <hip/hip_bf16.h>
#include <math.h>

#define NB 32768
#define DIM 512
#define KF 8
#define FEAT (DIM * 2 * KF)   // 8192 features per layer

#define BM 128
#define BN 128
#define BK 64                 // 4 inputs * 16 features
#define LDK 72                // padded LDS row length (bf16 elems); 144B rows -> conflict-free-ish

typedef __attribute__((ext_vector_type(8))) short bf16x8;
typedef __attribute__((ext_vector_type(4))) float f32x4;

static __device__ __forceinline__ unsigned short f2bf(float f) {
    union { float f; unsigned u; } v; v.f = f;
    unsigned r = v.u + 0x7fffu + ((v.u >> 16) & 1u);  // RNE
    return (unsigned short)(r >> 16);
}

// ---------------- pack A,B (fp32 [512][512][8]) -> Wt bf16 [512][8192] ----------------
// Wt[o][i*16 + j] = A[o][i][j] (j<8), B[o][i][j-8] (j>=8)
__global__ void pack_w(const float* __restrict__ A, const float* __restrict__ B,
                       unsigned short* __restrict__ Wt) {
    int idx = blockIdx.x * 256 + threadIdx.x;    // over 512*512 (o,i)
    int o = idx >> 9, i = idx & 511;
    const float* a = A + ((size_t)o * DIM + i) * KF;
    const float* b = B + ((size_t)o * DIM + i) * KF;
    bf16x8 v0, v1;
#pragma unroll
    for (int j = 0; j < 8; ++j) {
        v0[j] = (short)f2bf(a[j]);
        v1[j] = (short)f2bf(b[j]);
    }
    unsigned short* dst = Wt + (size_t)o * FEAT + i * 16;
    *(bf16x8*)dst = v0;
    *(bf16x8*)(dst + 8) = v1;
}

// ---------------- layer 0: in=1 -> out=512 ----------------
__global__ void layer0(const float* __restrict__ x, const float* __restrict__ A0,
                       const float* __restrict__ B0, float* __restrict__ Y) {
    int gid = blockIdx.x * 256 + threadIdx.x;    // over NB*512
    int b = gid >> 9, o = gid & 511;
    float xv = x[b];
    float s1, c1;
    __sincosf(xv, &s1, &c1);
    const float* a = A0 + o * KF;
    const float* bb = B0 + o * KF;
    float acc = bb[0];                 // k=0: sin term 0, cos term = B0[o][0]
    float sk = 0.f, ck = 1.f;
#pragma unroll
    for (int k = 1; k < KF; ++k) {
        float sn = sk * c1 + ck * s1;
        float cn = ck * c1 - sk * s1;
        sk = sn; ck = cn;
        acc += a[k] * sk + bb[k] * ck;
    }
    Y[gid] = acc;
}

// ---------------- fused feature+GEMM: Y[N][512] = F(X)[N][8192] * Wt[512][8192]^T ----------------
__global__ __launch_bounds__(256) void fkan_gemm(const float* __restrict__ X,
                                                 const unsigned short* __restrict__ Wt,
                                                 float* __restrict__ Y) {
    __shared__ unsigned short Alds[BM * LDK];
    __shared__ unsigned short Blds[BN * LDK];
    const int tid = threadIdx.x;
    const int bm0 = blockIdx.x * BM;   // 256 tiles
    const int bn0 = blockIdx.y * BN;   // 4 tiles
    const int wave = tid >> 6, lane = tid & 63;
    const int wr = wave >> 1, wc = wave & 1;      // 2x2 wave grid, each wave 64x64
    const int l15 = lane & 15, l4 = lane >> 4;

    f32x4 acc[4][4] = {};

    for (int t = 0; t < FEAT / BK; ++t) {         // 128 K-steps
        const int i0 = t * 4;                     // 4 inputs this step
        __syncthreads();
        // ---- stage A: compute 128 rows x 64 features into LDS ----
#pragma unroll
        for (int p = 0; p < 2; ++p) {
            int idx = tid + p * 256;              // 0..511 (b_local, input) pairs
            int bl = idx >> 2;                    // 0..127
            int ii = idx & 3;                     // 0..3
            float xv = X[(size_t)(bm0 + bl) * DIM + (i0 + ii)];
            float s1, c1;
            __sincosf(xv, &s1, &c1);
            bf16x8 vs, vc;
            vs[0] = 0;                            // sin(0*x)=0
            vc[0] = (short)0x3F80;                // cos(0*x)=1
            float sk = 0.f, ck = 1.f;
#pragma unroll
            for (int k = 1; k < KF; ++k) {
                float sn = sk * c1 + ck * s1;
                float cn = ck * c1 - sk * s1;
                sk = sn; ck = cn;
                vs[k] = (short)f2bf(sk);
                vc[k] = (short)f2bf(ck);
            }
            unsigned short* dst = &Alds[bl * LDK + ii * 16];
            *(bf16x8*)dst = vs;
            *(bf16x8*)(dst + 8) = vc;
        }
        // ---- stage B: 128 out-rows x 64 features from packed Wt ----
#pragma unroll
        for (int q = 0; q < 4; ++q) {
            int u = tid + q * 256;                // 0..1023 16B units
            int row = u >> 3;                     // 0..127
            int c = u & 7;
            const unsigned short* src = Wt + (size_t)(bn0 + row) * FEAT + t * BK + c * 8;
            bf16x8 v = *(const bf16x8*)src;
            *(bf16x8*)&Blds[row * LDK + c * 8] = v;
        }
        __syncthreads();
        // ---- MFMA ----
#pragma unroll
        for (int kk = 0; kk < 2; ++kk) {
            bf16x8 af[4], bfr[4];
#pragma unroll
            for (int m = 0; m < 4; ++m)
                af[m] = *(bf16x8*)&Alds[(wr * 64 + m * 16 + l15) * LDK + kk * 32 + l4 * 8];
#pragma unroll
            for (int n = 0; n < 4; ++n)
                bfr[n] = *(bf16x8*)&Blds[(wc * 64 + n * 16 + l15) * LDK + kk * 32 + l4 * 8];
#pragma unroll
            for (int m = 0; m < 4; ++m)
#pragma unroll
                for (int n = 0; n < 4; ++n)
                    acc[m][n] = __builtin_amdgcn_mfma_f32_16x16x32_bf16(af[m], bfr[n], acc[m][n], 0, 0, 0);
        }
    }
    // ---- epilogue: C/D layout col=lane&15, row=(lane>>4)*4+reg ----
#pragma unroll
    for (int m = 0; m < 4; ++m)
#pragma unroll
        for (int n = 0; n < 4; ++n)
#pragma unroll
            for (int j = 0; j < 4; ++j) {
                int row = bm0 + wr * 64 + m * 16 + l4 * 4 + j;
                int col = bn0 + wc * 64 + n * 16 + l15;
                Y[(size_t)row * DIM + col] = acc[m][n][j];
            }
}

// ---------------- layer 4: in=512 -> out=1, one wave per row ----------------
__global__ void layer4(const float* __restrict__ X, const float* __restrict__ A4,
                       const float* __restrict__ B4, float* __restrict__ Y) {
    int wave = threadIdx.x >> 6, lane = threadIdx.x & 63;
    int b = blockIdx.x * 4 + wave;
    float acc = 0.f;
#pragma unroll
    for (int ii = 0; ii < 8; ++ii) {
        int i = lane + ii * 64;
        float xv = X[(size_t)b * DIM + i];
        float s1, c1;
        __sincosf(xv, &s1, &c1);
        const float* a = A4 + i * KF;
        const float* bb = B4 + i * KF;
        acc += bb[0];
        float sk = 0.f, ck = 1.f;
#pragma unroll
        for (int k = 1; k < KF; ++k) {
            float sn = sk * c1 + ck * s1;
            float cn = ck * c1 - sk * s1;
            sk = sn; ck = cn;
            acc += a[k] * sk + bb[k] * ck;
        }
    }
#pragma unroll
    for (int off = 32; off > 0; off >>= 1) acc += __shfl_down(acc, off, 64);
    if (lane == 0) Y[b] = acc;
}

extern "C" void kernel_launch(void* const* d_in, const int* in_sizes, int n_in,
                              void* d_out, int out_size, void* d_ws, size_t ws_size,
                              hipStream_t stream) {
    const float* x  = (const float*)d_in[0];
    const float* A0 = (const float*)d_in[1];
    const float* B0 = (const float*)d_in[2];
    const float* A1 = (const float*)d_in[3];
    const float* B1 = (const float*)d_in[4];
    const float* A2 = (const float*)d_in[5];
    const float* B2 = (const float*)d_in[6];
    const float* A3 = (const float*)d_in[7];
    const float* B3 = (const float*)d_in[8];
    const float* A4 = (const float*)d_in[9];
    const float* B4 = (const float*)d_in[10];
    float* out = (float*)d_out;

    char* ws = (char*)d_ws;
    const size_t actBytes = (size_t)NB * DIM * sizeof(float);   // 64 MB
    float* bufA = (float*)ws;
    float* bufB = (float*)(ws + actBytes);
    unsigned short* W1 = (unsigned short*)(ws + 2 * actBytes);
    unsigned short* W2 = W1 + (size_t)DIM * FEAT;
    unsigned short* W3 = W2 + (size_t)DIM * FEAT;

    pack_w<<<DIM * DIM / 256, 256, 0, stream>>>(A1, B1, W1);
    pack_w<<<DIM * DIM / 256, 256, 0, stream>>>(A2, B2, W2);
    pack_w<<<DIM * DIM / 256, 256, 0, stream>>>(A3, B3, W3);

    layer0<<<(NB * DIM) / 256, 256, 0, stream>>>(x, A0, B0, bufA);

    dim3 grid(NB / BM, DIM / BN);
    fkan_gemm<<<grid, 256, 0, stream>>>(bufA, W1, bufB);
    fkan_gemm<<<grid, 256, 0, stream>>>(bufB, W2, bufA);
    fkan_gemm<<<grid, 256, 0, stream>>>(bufA, W3, bufB);

    layer4<<<NB / 4, 256, 0, stream>>>(bufB, A4, B4, out);
}

// Round 2
// 907.952 us; speedup vs baseline: 1.3554x; 1.3554x over previous
//
#include <hip/hip_runtime.h>
#include <hip/hip_bf16.h>
#include <math.h>

#define NB 32768
#define DIM 512
#define KF 8
#define FEAT 8192
#define BM 128
#define BK 64
#define NSTEP (FEAT / BK)   // 128

typedef __attribute__((ext_vector_type(8))) short bf16x8;
typedef __attribute__((ext_vector_type(4))) float f32x4;

static __device__ __forceinline__ short f2bf(float f) {
    union { __hip_bfloat16 h; short s; } u;
    u.h = __float2bfloat16(f);
    return u.s;
}

// global(16B per lane, per-lane addr) -> LDS (wave-uniform base + lane*16)
static __device__ __forceinline__ void stage16(const unsigned short* g, unsigned short* l, int lane) {
#if defined(__has_builtin) && __has_builtin(__builtin_amdgcn_global_load_lds)
    __builtin_amdgcn_global_load_lds((const __attribute__((address_space(1))) unsigned int*)g,
                                     (__attribute__((address_space(3))) unsigned int*)l, 16, 0, 0);
#else
    *(bf16x8*)(l + lane * 8) = *(const bf16x8*)g;
#endif
}

// ---------------- pack A,B (fp32 [512][512][8]) -> Wt bf16 [512][8192] ----------------
// Wt[o][i*16 + j] = A[o][i][j] (j<8), B[o][i][j-8] (j>=8)
__global__ void pack_w(const float* __restrict__ A, const float* __restrict__ B,
                       unsigned short* __restrict__ Wt) {
    int idx = blockIdx.x * 256 + threadIdx.x;    // over 512*512 (o,i)
    int o = idx >> 9, i = idx & 511;
    const float* a = A + ((size_t)o * DIM + i) * KF;
    const float* b = B + ((size_t)o * DIM + i) * KF;
    bf16x8 v0, v1;
#pragma unroll
    for (int j = 0; j < 8; ++j) {
        v0[j] = f2bf(a[j]);
        v1[j] = f2bf(b[j]);
    }
    unsigned short* dst = Wt + (size_t)o * FEAT + i * 16;
    *(bf16x8*)dst = v0;
    *(bf16x8*)(dst + 8) = v1;
}

// ---------------- layer 0: in=1 -> out=512 ----------------
__global__ void layer0(const float* __restrict__ x, const float* __restrict__ A0,
                       const float* __restrict__ B0, float* __restrict__ Y) {
    int gid = blockIdx.x * 256 + threadIdx.x;    // over NB*512
    int b = gid >> 9, o = gid & 511;
    float xv = x[b];
    float s1, c1;
    __sincosf(xv, &s1, &c1);
    const float* a = A0 + o * KF;
    const float* bb = B0 + o * KF;
    float acc = bb[0];
    float sk = 0.f, ck = 1.f;
#pragma unroll
    for (int k = 1; k < KF; ++k) {
        float sn = sk * c1 + ck * s1;
        float cn = ck * c1 - sk * s1;
        sk = sn; ck = cn;
        acc += a[k] * sk + bb[k] * ck;
    }
    Y[gid] = acc;
}

// ---------------- fused feature+GEMM: Y[N][512] = F(X)[N][8192] * Wt[512][8192]^T ----------------
// BM=128 rows per block, full N=512 per block (zero feature recompute).
// LDS tiles row stride 64 elems (128B = 8 16B-units); unit index XOR-swizzled with (row&7).
__global__ __launch_bounds__(512, 2) void fkan_gemm(const float* __restrict__ X,
                                                    const unsigned short* __restrict__ Wt,
                                                    float* __restrict__ Y) {
    __shared__ unsigned short Alds[BM * BK];     // 16 KB
    __shared__ unsigned short Blds[DIM * BK];    // 64 KB
    const int tid = threadIdx.x;
    const int lane = tid & 63, wave = tid >> 6;
    const int wr = wave >> 2, wc = wave & 3;     // 2x4 wave grid, wave tile 64x128
    const int l15 = lane & 15, l4 = lane >> 4;
    const int bm0 = blockIdx.x * BM;

    // A staging: one (row, input) item per thread
    const int bl = tid >> 2, ii = tid & 3;
    const float* xp = X + (size_t)(bm0 + bl) * DIM + ii;
    const int au0 = (((ii * 2) ^ (bl & 7)) * 8) + bl * BK;
    const int au1 = (((ii * 2 + 1) ^ (bl & 7)) * 8) + bl * BK;

    // B staging: 4096 16B-units; per-wave 8 calls of 64 lanes.
    // LDS slot u=(row, c) must hold global unit (c ^ (row&7)) -> pre-swizzled source.
    int srcoff[8];
#pragma unroll
    for (int q = 0; q < 8; ++q) {
        int u = wave * 512 + q * 64 + lane;
        int row = u >> 3, c = u & 7;
        srcoff[q] = row * FEAT + ((c ^ (row & 7)) * 8);
    }

    f32x4 acc[4][8];
#pragma unroll
    for (int m = 0; m < 4; ++m)
#pragma unroll
        for (int n = 0; n < 8; ++n) acc[m][n] = (f32x4)0.f;

    float xv = xp[0];
    for (int t = 0; t < NSTEP; ++t) {
        // ---- issue B tile loads first (latency hides under feature VALU) ----
#pragma unroll
        for (int q = 0; q < 8; ++q)
            stage16(Wt + srcoff[q] + t * BK, &Blds[(wave * 512 + q * 64) * 8], lane);
        // ---- compute 16 features for this thread's (row, input) ----
        float s1, c1;
        __sincosf(xv, &s1, &c1);
        bf16x8 vs, vc;
        vs[0] = 0;
        vc[0] = (short)0x3F80;
        float sk = 0.f, ck = 1.f;
#pragma unroll
        for (int k = 1; k < KF; ++k) {
            float sn = sk * c1 + ck * s1;
            float cn = ck * c1 - sk * s1;
            sk = sn; ck = cn;
            vs[k] = f2bf(sk);
            vc[k] = f2bf(ck);
        }
        *(bf16x8*)&Alds[au0] = vs;
        *(bf16x8*)&Alds[au1] = vc;
        if (t + 1 < NSTEP) xv = xp[(t + 1) * 4];   // prefetch next x
        __syncthreads();
        // ---- MFMA: wave tile 64x128, 64 MFMA per step ----
#pragma unroll
        for (int kk = 0; kk < 2; ++kk) {
            const int up = (((kk * 4 + l4) ^ (l15 & 7)) * 8);
            bf16x8 af[4], bfr[8];
#pragma unroll
            for (int m = 0; m < 4; ++m)
                af[m] = *(bf16x8*)&Alds[(wr * 64 + m * 16 + l15) * BK + up];
#pragma unroll
            for (int n = 0; n < 8; ++n)
                bfr[n] = *(bf16x8*)&Blds[(wc * 128 + n * 16 + l15) * BK + up];
#pragma unroll
            for (int m = 0; m < 4; ++m)
#pragma unroll
                for (int n = 0; n < 8; ++n)
                    acc[m][n] = __builtin_amdgcn_mfma_f32_16x16x32_bf16(af[m], bfr[n], acc[m][n], 0, 0, 0);
        }
        __syncthreads();
    }
    // ---- epilogue: C/D layout col=lane&15, row=(lane>>4)*4+reg ----
#pragma unroll
    for (int m = 0; m < 4; ++m)
#pragma unroll
        for (int n = 0; n < 8; ++n)
#pragma unroll
            for (int j = 0; j < 4; ++j) {
                int row = bm0 + wr * 64 + m * 16 + l4 * 4 + j;
                int col = wc * 128 + n * 16 + l15;
                Y[(size_t)row * DIM + col] = acc[m][n][j];
            }
}

// ---------------- layer 4: in=512 -> out=1, one wave per row ----------------
__global__ void layer4(const float* __restrict__ X, const float* __restrict__ A4,
                       const float* __restrict__ B4, float* __restrict__ Y) {
    int wave = threadIdx.x >> 6, lane = threadIdx.x & 63;
    int b = blockIdx.x * 4 + wave;
    float acc = 0.f;
#pragma unroll
    for (int ii = 0; ii < 8; ++ii) {
        int i = lane + ii * 64;
        float xv = X[(size_t)b * DIM + i];
        float s1, c1;
        __sincosf(xv, &s1, &c1);
        const float* a = A4 + i * KF;
        const float* bb = B4 + i * KF;
        acc += bb[0];
        float sk = 0.f, ck = 1.f;
#pragma unroll
        for (int k = 1; k < KF; ++k) {
            float sn = sk * c1 + ck * s1;
            float cn = ck * c1 - sk * s1;
            sk = sn; ck = cn;
            acc += a[k] * sk + bb[k] * ck;
        }
    }
#pragma unroll
    for (int off = 32; off > 0; off >>= 1) acc += __shfl_down(acc, off, 64);
    if (lane == 0) Y[b] = acc;
}

extern "C" void kernel_launch(void* const* d_in, const int* in_sizes, int n_in,
                              void* d_out, int out_size, void* d_ws, size_t ws_size,
                              hipStream_t stream) {
    const float* x  = (const float*)d_in[0];
    const float* A0 = (const float*)d_in[1];
    const float* B0 = (const float*)d_in[2];
    const float* A1 = (const float*)d_in[3];
    const float* B1 = (const float*)d_in[4];
    const float* A2 = (const float*)d_in[5];
    const float* B2 = (const float*)d_in[6];
    const float* A3 = (const float*)d_in[7];
    const float* B3 = (const float*)d_in[8];
    const float* A4 = (const float*)d_in[9];
    const float* B4 = (const float*)d_in[10];
    float* out = (float*)d_out;

    char* ws = (char*)d_ws;
    const size_t actBytes = (size_t)NB * DIM * sizeof(float);   // 64 MB
    float* bufA = (float*)ws;
    float* bufB = (float*)(ws + actBytes);
    unsigned short* W1 = (unsigned short*)(ws + 2 * actBytes);
    unsigned short* W2 = W1 + (size_t)DIM * FEAT;
    unsigned short* W3 = W2 + (size_t)DIM * FEAT;

    pack_w<<<DIM * DIM / 256, 256, 0, stream>>>(A1, B1, W1);
    pack_w<<<DIM * DIM / 256, 256, 0, stream>>>(A2, B2, W2);
    pack_w<<<DIM * DIM / 256, 256, 0, stream>>>(A3, B3, W3);

    layer0<<<(NB * DIM) / 256, 256, 0, stream>>>(x, A0, B0, bufA);

    fkan_gemm<<<NB / BM, 512, 0, stream>>>(bufA, W1, bufB);
    fkan_gemm<<<NB / BM, 512, 0, stream>>>(bufB, W2, bufA);
    fkan_gemm<<<NB / BM, 512, 0, stream>>>(bufA, W3, bufB);

    layer4<<<NB / 4, 256, 0, stream>>>(bufB, A4, B4, out);
}

// Round 3
// 803.901 us; speedup vs baseline: 1.5309x; 1.1294x over previous
//
#include <hip/hip_runtime.h>
#include <hip/hip_bf16.h>
#include <math.h>

#define NB 32768
#define DIM 512
#define KF 8
#define FEAT 8192
#define BM 128
#define BK 64
#define NSTEP (FEAT / BK)   // 128

typedef __attribute__((ext_vector_type(8))) short bf16x8;
typedef __attribute__((ext_vector_type(4))) float f32x4;

static __device__ __forceinline__ short f2bf(float f) {
    union { __hip_bfloat16 h; short s; } u;
    u.h = __float2bfloat16(f);
    return u.s;
}

// global(16B per lane, per-lane addr) -> LDS (wave-uniform base + lane*16)
static __device__ __forceinline__ void stage16(const unsigned short* g, unsigned short* l, int lane) {
    __builtin_amdgcn_global_load_lds((const __attribute__((address_space(1))) unsigned int*)g,
                                     (__attribute__((address_space(3))) unsigned int*)l, 16, 0, 0);
}

// ---------------- pack A,B (fp32 [512][512][8]) -> Wt bf16 [512][8192] ----------------
// Wt[o][i*16 + j] = A[o][i][j] (j<8), B[o][i][j-8] (j>=8)
__global__ void pack_w(const float* __restrict__ A, const float* __restrict__ B,
                       unsigned short* __restrict__ Wt) {
    int idx = blockIdx.x * 256 + threadIdx.x;    // over 512*512 (o,i)
    int o = idx >> 9, i = idx & 511;
    const float* a = A + ((size_t)o * DIM + i) * KF;
    const float* b = B + ((size_t)o * DIM + i) * KF;
    bf16x8 v0, v1;
#pragma unroll
    for (int j = 0; j < 8; ++j) {
        v0[j] = f2bf(a[j]);
        v1[j] = f2bf(b[j]);
    }
    unsigned short* dst = Wt + (size_t)o * FEAT + i * 16;
    *(bf16x8*)dst = v0;
    *(bf16x8*)(dst + 8) = v1;
}

// ---------------- layer 0: in=1 -> out=512 ----------------
__global__ void layer0(const float* __restrict__ x, const float* __restrict__ A0,
                       const float* __restrict__ B0, float* __restrict__ Y) {
    int gid = blockIdx.x * 256 + threadIdx.x;    // over NB*512
    int b = gid >> 9, o = gid & 511;
    float xv = x[b];
    float s1, c1;
    __sincosf(xv, &s1, &c1);
    const float* a = A0 + o * KF;
    const float* bb = B0 + o * KF;
    float acc = bb[0];
    float sk = 0.f, ck = 1.f;
#pragma unroll
    for (int k = 1; k < KF; ++k) {
        float sn = sk * c1 + ck * s1;
        float cn = ck * c1 - sk * s1;
        sk = sn; ck = cn;
        acc += a[k] * sk + bb[k] * ck;
    }
    Y[gid] = acc;
}

// ---------------- fused feature+GEMM: Y[N][512] = F(X)[N][8192] * Wt[512][8192]^T ----------------
// BM=128 rows per block, full N=512 per block. Double-buffered LDS, ONE barrier per K-step:
// issue B-stage(t+1) + compute A-feat(t+1) -> other buffer, MFMA on current, syncthreads.
// Row stride 64 elems (128B = 8 16B-units); unit index XOR-swizzled with (row&7).
__global__ __launch_bounds__(512, 2) void fkan_gemm(const float* __restrict__ X,
                                                    const unsigned short* __restrict__ Wt,
                                                    float* __restrict__ Y) {
    __shared__ unsigned short Alds[2][BM * BK];   // 2 x 16 KB
    __shared__ unsigned short Blds[2][DIM * BK];  // 2 x 64 KB   (total 160 KB)
    const int tid = threadIdx.x;
    const int lane = tid & 63, wave = tid >> 6;
    const int wr = wave >> 2, wc = wave & 3;     // 2x4 wave grid, wave tile 64x128
    const int l15 = lane & 15, l4 = lane >> 4;
    const int bm0 = blockIdx.x * BM;

    // A staging: one (row, input) item per thread
    const int bl = tid >> 2, ii = tid & 3;
    const float* xp = X + (size_t)(bm0 + bl) * DIM + ii;
    const int au0 = (((ii * 2) ^ (bl & 7)) * 8) + bl * BK;
    const int au1 = (((ii * 2 + 1) ^ (bl & 7)) * 8) + bl * BK;

    // B staging: 4096 16B-units; per-wave 8 calls of 64 lanes.
    // LDS slot u=(row, c) must hold global unit (c ^ (row&7)) -> pre-swizzled source.
    int srcoff[8];
#pragma unroll
    for (int q = 0; q < 8; ++q) {
        int u = wave * 512 + q * 64 + lane;
        int row = u >> 3, c = u & 7;
        srcoff[q] = row * FEAT + ((c ^ (row & 7)) * 8);
    }

    f32x4 acc[4][8];
#pragma unroll
    for (int m = 0; m < 4; ++m)
#pragma unroll
        for (int n = 0; n < 8; ++n) acc[m][n] = (f32x4)0.f;

    // ---- prologue: fill buffer 0 for t=0 ----
    float xv = xp[0];
    {
#pragma unroll
        for (int q = 0; q < 8; ++q)
            stage16(Wt + srcoff[q], &Blds[0][(wave * 512 + q * 64) * 8], lane);
        float s1, c1;
        __sincosf(xv, &s1, &c1);
        bf16x8 vs, vc;
        vs[0] = 0;
        vc[0] = (short)0x3F80;
        float sk = 0.f, ck = 1.f;
#pragma unroll
        for (int k = 1; k < KF; ++k) {
            float sn = sk * c1 + ck * s1;
            float cn = ck * c1 - sk * s1;
            sk = sn; ck = cn;
            vs[k] = f2bf(sk);
            vc[k] = f2bf(ck);
        }
        *(bf16x8*)&Alds[0][au0] = vs;
        *(bf16x8*)&Alds[0][au1] = vc;
        xv = xp[4];   // x for t=1
    }
    __syncthreads();

    int cur = 0;
    for (int t = 0; t < NSTEP; ++t) {
        const int nxt = cur ^ 1;
        // ---- phase 1: prefetch t+1 into the other buffer ----
        if (t + 1 < NSTEP) {
#pragma unroll
            for (int q = 0; q < 8; ++q)
                stage16(Wt + srcoff[q] + (t + 1) * BK, &Blds[nxt][(wave * 512 + q * 64) * 8], lane);
            float s1, c1;
            __sincosf(xv, &s1, &c1);
            bf16x8 vs, vc;
            vs[0] = 0;
            vc[0] = (short)0x3F80;
            float sk = 0.f, ck = 1.f;
#pragma unroll
            for (int k = 1; k < KF; ++k) {
                float sn = sk * c1 + ck * s1;
                float cn = ck * c1 - sk * s1;
                sk = sn; ck = cn;
                vs[k] = f2bf(sk);
                vc[k] = f2bf(ck);
            }
            *(bf16x8*)&Alds[nxt][au0] = vs;
            *(bf16x8*)&Alds[nxt][au1] = vc;
            if (t + 2 < NSTEP) xv = xp[(t + 2) * 4];
        }
        // ---- phase 2: MFMA on current buffer (64 MFMA / wave / step) ----
        const unsigned short* Ab = &Alds[cur][0];
        const unsigned short* Bb = &Blds[cur][0];
#pragma unroll
        for (int kk = 0; kk < 2; ++kk) {
            const int up = (((kk * 4 + l4) ^ (l15 & 7)) * 8);
            bf16x8 af[4], bfr[8];
#pragma unroll
            for (int m = 0; m < 4; ++m)
                af[m] = *(bf16x8*)&Ab[(wr * 64 + m * 16 + l15) * BK + up];
#pragma unroll
            for (int n = 0; n < 8; ++n)
                bfr[n] = *(bf16x8*)&Bb[(wc * 128 + n * 16 + l15) * BK + up];
#pragma unroll
            for (int m = 0; m < 4; ++m)
#pragma unroll
                for (int n = 0; n < 8; ++n)
                    acc[m][n] = __builtin_amdgcn_mfma_f32_16x16x32_bf16(af[m], bfr[n], acc[m][n], 0, 0, 0);
        }
        // ---- single barrier per step (drains vmcnt for loads issued ~2500cy ago) ----
        __syncthreads();
        cur = nxt;
    }
    // ---- epilogue: C/D layout col=lane&15, row=(lane>>4)*4+reg ----
#pragma unroll
    for (int m = 0; m < 4; ++m)
#pragma unroll
        for (int n = 0; n < 8; ++n)
#pragma unroll
            for (int j = 0; j < 4; ++j) {
                int row = bm0 + wr * 64 + m * 16 + l4 * 4 + j;
                int col = wc * 128 + n * 16 + l15;
                Y[(size_t)row * DIM + col] = acc[m][n][j];
            }
}

// ---------------- layer 4: in=512 -> out=1, one wave per row ----------------
__global__ void layer4(const float* __restrict__ X, const float* __restrict__ A4,
                       const float* __restrict__ B4, float* __restrict__ Y) {
    int wave = threadIdx.x >> 6, lane = threadIdx.x & 63;
    int b = blockIdx.x * 4 + wave;
    float acc = 0.f;
#pragma unroll
    for (int ii = 0; ii < 8; ++ii) {
        int i = lane + ii * 64;
        float xv = X[(size_t)b * DIM + i];
        float s1, c1;
        __sincosf(xv, &s1, &c1);
        const float* a = A4 + i * KF;
        const float* bb = B4 + i * KF;
        acc += bb[0];
        float sk = 0.f, ck = 1.f;
#pragma unroll
        for (int k = 1; k < KF; ++k) {
            float sn = sk * c1 + ck * s1;
            float cn = ck * c1 - sk * s1;
            sk = sn; ck = cn;
            acc += a[k] * sk + bb[k] * ck;
        }
    }
#pragma unroll
    for (int off = 32; off > 0; off >>= 1) acc += __shfl_down(acc, off, 64);
    if (lane == 0) Y[b] = acc;
}

extern "C" void kernel_launch(void* const* d_in, const int* in_sizes, int n_in,
                              void* d_out, int out_size, void* d_ws, size_t ws_size,
                              hipStream_t stream) {
    const float* x  = (const float*)d_in[0];
    const float* A0 = (const float*)d_in[1];
    const float* B0 = (const float*)d_in[2];
    const float* A1 = (const float*)d_in[3];
    const float* B1 = (const float*)d_in[4];
    const float* A2 = (const float*)d_in[5];
    const float* B2 = (const float*)d_in[6];
    const float* A3 = (const float*)d_in[7];
    const float* B3 = (const float*)d_in[8];
    const float* A4 = (const float*)d_in[9];
    const float* B4 = (const float*)d_in[10];
    float* out = (float*)d_out;

    char* ws = (char*)d_ws;
    const size_t actBytes = (size_t)NB * DIM * sizeof(float);   // 64 MB
    float* bufA = (float*)ws;
    float* bufB = (float*)(ws + actBytes);
    unsigned short* W1 = (unsigned short*)(ws + 2 * actBytes);
    unsigned short* W2 = W1 + (size_t)DIM * FEAT;
    unsigned short* W3 = W2 + (size_t)DIM * FEAT;

    pack_w<<<DIM * DIM / 256, 256, 0, stream>>>(A1, B1, W1);
    pack_w<<<DIM * DIM / 256, 256, 0, stream>>>(A2, B2, W2);
    pack_w<<<DIM * DIM / 256, 256, 0, stream>>>(A3, B3, W3);

    layer0<<<(NB * DIM) / 256, 256, 0, stream>>>(x, A0, B0, bufA);

    fkan_gemm<<<NB / BM, 512, 0, stream>>>(bufA, W1, bufB);
    fkan_gemm<<<NB / BM, 512, 0, stream>>>(bufB, W2, bufA);
    fkan_gemm<<<NB / BM, 512, 0, stream>>>(bufA, W3, bufB);

    layer4<<<NB / 4, 256, 0, stream>>>(bufB, A4, B4, out);
}